// Round 8
// baseline (242.907 us; speedup 1.0000x reference)
//
#include <hip/hip_runtime.h>
#include <stdint.h>

#define HT_STRIDE 262144   // 4096*64 elements per head

typedef __attribute__((ext_vector_type(8))) short bf16x8;
typedef __attribute__((ext_vector_type(4))) float f32x4;

__device__ __forceinline__ unsigned short f2bf(float f) {
    unsigned int u = __float_as_uint(f);
    u += 0x7FFFu + ((u >> 16) & 1u);
    return (unsigned short)(u >> 16);
}
__device__ __forceinline__ unsigned int pack2bf(float lo, float hi) {
    return (unsigned int)f2bf(lo) | ((unsigned int)f2bf(hi) << 16);
}

// ---------------------------------------------------------------------------
// Kernel A: ht = h(4096x128) @ W(128x512) f32, into d_out. Epilogue computes
// src/tgt. Reshape semantics: ht[head][i][o] = hW_flat[head*262144+i*64+o],
// i.e. hW element (n,c) -> head = n>>9, i = (n&511)*8 + (c>>6), o = c&63.
// (R6/R7 bug: used head=c>>6, i=n. Fixed here.)
// ---------------------------------------------------------------------------
__global__ void __launch_bounds__(256) k_linear(const float* __restrict__ h,
                                                const float* __restrict__ W,
                                                const float* __restrict__ aW,
                                                float* __restrict__ ht,
                                                float* __restrict__ src,
                                                float* __restrict__ tgt) {
    __shared__ float hs[8][128];
    const int t = threadIdx.x;
    const int n0 = blockIdx.x * 8;
    {
        float4 v = ((const float4*)(h + n0 * 128))[t];
        int e = t * 4;
        int r = e >> 7, f = e & 127;
        hs[r][f + 0] = v.x; hs[r][f + 1] = v.y;
        hs[r][f + 2] = v.z; hs[r][f + 3] = v.w;
    }
    __syncthreads();
    float acc0[8], acc1[8];
    #pragma unroll
    for (int r = 0; r < 8; ++r) { acc0[r] = 0.f; acc1[r] = 0.f; }
    const float2* Wf = (const float2*)W;
    for (int f = 0; f < 128; ++f) {
        float2 wp = Wf[f * 256 + t];
        #pragma unroll
        for (int r = 0; r < 8; ++r) {
            float hv = hs[r][f];
            acc0[r] = fmaf(hv, wp.x, acc0[r]);
            acc1[r] = fmaf(hv, wp.y, acc1[r]);
        }
    }
    float2* ob = (float2*)ht;
    #pragma unroll
    for (int r = 0; r < 8; ++r) {
        ob[(n0 + r) * 256 + t] = make_float2(acc0[r], acc1[r]);
    }
    // ---- corrected src/tgt epilogue ----
    const int hb = blockIdx.x >> 6;        // head = n>>9, uniform over the 8 rows
    const int g  = t >> 5;                 // c>>6 within the 512 cols (0..7)
    const int o0 = (2 * t) & 63;           // o for acc0; acc1 is o0+1
    const float a1x = aW[hb * 128 + o0],      a1y = aW[hb * 128 + o0 + 1];
    const float a2x = aW[hb * 128 + 64 + o0], a2y = aW[hb * 128 + 64 + o0 + 1];
    const int ib = ((n0 & 511) << 3) + g;  // i for row r is ib + r*8
    #pragma unroll
    for (int r = 0; r < 8; ++r) {
        float s  = acc0[r] * a1x + acc1[r] * a1y;
        float gg = acc0[r] * a2x + acc1[r] * a2y;
        #pragma unroll
        for (int off = 16; off > 0; off >>= 1) {
            s  += __shfl_down(s,  off, 32);
            gg += __shfl_down(gg, off, 32);
        }
        if ((t & 31) == 0) {
            src[hb * 4096 + ib + r * 8] = s;
            tgt[hb * 4096 + ib + r * 8] = gg;
        }
    }
}

// ---------------------------------------------------------------------------
// Kernel A2: htT2[hd][m>>5][o][m&31] = bf16(ht_flat[hd*262144 + m*64 + o]).
// Flat-indexed, so it is reshape-correct by definition (R4-proven).
// ---------------------------------------------------------------------------
__global__ void __launch_bounds__(256) k_transpose(const float* __restrict__ ht,
                                                   unsigned short* __restrict__ htT2) {
    __shared__ unsigned short tile[64][65];
    const int t = threadIdx.x;
    const int hd = blockIdx.x >> 6;
    const int m0 = (blockIdx.x & 63) * 64;
    const float* s = ht + hd * HT_STRIDE + m0 * 64;
    #pragma unroll
    for (int i = 0; i < 16; ++i) {
        int idx = t + 256 * i;
        tile[idx >> 6][idx & 63] = f2bf(s[idx]);
    }
    __syncthreads();
    unsigned short* d = htT2 + hd * HT_STRIDE + (m0 >> 5) * 2048;
    #pragma unroll
    for (int i = 0; i < 16; ++i) {
        int idx = t + 256 * i;
        int o = idx >> 6, mi = idx & 63;
        d[(mi >> 5) * 2048 + o * 32 + (mi & 31)] = tile[mi][o];
    }
}

// ---------------------------------------------------------------------------
// Kernel C: per head: tmax + exp tables E1=exp(tgt), E2=exp(0.2*tgt).
// Identity: exp(lrelu(e)) = max(exp(e), exp(0.2e)) and e = sv+tt separates.
// ---------------------------------------------------------------------------
__global__ void __launch_bounds__(256) k_expmax(const float* __restrict__ tgt,
                                                float* __restrict__ tmax,
                                                float* __restrict__ E1,
                                                float* __restrict__ E2) {
    __shared__ float red[256];
    const int t = threadIdx.x;
    const int hd = blockIdx.x;
    float m = -1e30f;
    for (int i = t; i < 4096; i += 256) {
        float v = tgt[hd * 4096 + i];
        E1[hd * 4096 + i] = __expf(v);
        E2[hd * 4096 + i] = __expf(0.2f * v);
        m = fmaxf(m, v);
    }
    red[t] = m;
    __syncthreads();
    for (int s2 = 128; s2 > 0; s2 >>= 1) {
        if (t < s2) red[t] = fmaxf(red[t], red[t + s2]);
        __syncthreads();
    }
    if (t == 0) tmax[hd] = red[0];
}

// ---------------------------------------------------------------------------
// Kernel M: adjacency -> packed bitmask (4096 rows x 128 words). One wave/row.
// ---------------------------------------------------------------------------
__global__ void __launch_bounds__(256) k_maskbuild(const int* __restrict__ adj,
                                                   unsigned int* __restrict__ bmg) {
    const int wave = threadIdx.x >> 6, lane = threadIdx.x & 63;
    const int row = blockIdx.x * 4 + wave;
    const int* arow = adj + row * 4096;
    #pragma unroll 4
    for (int s = 0; s < 64; ++s) {
        int v = arow[s * 64 + lane];
        unsigned long long m = __ballot(v > 0);
        if (lane < 2) bmg[row * 128 + s * 2 + lane] = (unsigned int)(m >> (lane * 32));
    }
}

// ---------------------------------------------------------------------------
// Kernel D v3b: fused GAT attention, exp-free hot loop.
// block = 512 thr = 8 waves = 2 heads x 4 k-quarters; grid = 1024 blocks.
// ---------------------------------------------------------------------------
__global__ void __launch_bounds__(512) k_attn(const int* __restrict__ adj,
                                              const unsigned int* __restrict__ bmg,
                                              const int use_bmg,
                                              const unsigned short* __restrict__ htT2,
                                              const float* __restrict__ src,
                                              const float* __restrict__ E1,
                                              const float* __restrict__ E2,
                                              const float* __restrict__ tmax,
                                              float* __restrict__ out) {
    __shared__ unsigned int bm[16 * 132];     // 16 rows x 128 words, stride 132
    __shared__ float comb[2][3][64][17];      // [headLocal][writer kq-1][lane][acc16+pd]

    const int t = threadIdx.x;
    const int wave = t >> 6, lane = t & 63;
    const int hl = wave >> 2, kq = wave & 3;
    const int li = lane & 15, quad = lane >> 4;
    const int stripe = blockIdx.x >> 2, hg = blockIdx.x & 3;
    const int head = hg * 2 + hl;
    const int i0 = stripe * 16;

    if (use_bmg) {
        int w = t * 4;
        int row = w >> 7, col = w & 127;
        uint4 g = *((const uint4*)(bmg + (i0 + row) * 128 + col));
        *((uint4*)&bm[row * 132 + col]) = g;
    } else {
        #pragma unroll
        for (int rr = 0; rr < 2; ++rr) {
            const int rloc = wave * 2 + rr;
            const int* arow = adj + (i0 + rloc) * 4096;
            for (int s = 0; s < 64; ++s) {
                int v = arow[s * 64 + lane];
                unsigned long long m = __ballot(v > 0);
                if (lane < 2) bm[rloc * 132 + s * 2 + lane] = (unsigned int)(m >> (lane * 32));
            }
        }
    }
    __syncthreads();

    const float sv = src[head * 4096 + i0 + li];
    const float tm0 = sv + tmax[head];
    const float mi = fmaxf(tm0, 0.2f * tm0);  // >= lrelu(e) for every j (monotone)
    const float C1 = __expf(sv - mi);
    const float C2 = __expf(0.2f * sv - mi);

    f32x4 acc[4];
    #pragma unroll
    for (int f = 0; f < 4; ++f) acc[f] = (f32x4){0.f, 0.f, 0.f, 0.f};
    float pd = 0.f;

    const float4* e1p = (const float4*)(E1 + head * 4096);
    const float4* e2p = (const float4*)(E2 + head * 4096);
    const uint4*  ap  = (const uint4*)(htT2 + head * HT_STRIDE);
    const unsigned int* bmr = bm + li * 132;

    const int c0 = kq * 32;
    for (int c = 0; c < 32; ++c) {
        const int cc = c0 + c;
        const unsigned int word = bmr[cc];
        const int kb = cc * 32 + quad * 8;
        const float4 e1a = e1p[(kb >> 2) + 0];
        const float4 e1b = e1p[(kb >> 2) + 1];
        const float4 e2a = e2p[(kb >> 2) + 0];
        const float4 e2b = e2p[(kb >> 2) + 1];

        float wv[8];
        wv[0] = fmaxf(C1 * e1a.x, C2 * e2a.x);
        wv[1] = fmaxf(C1 * e1a.y, C2 * e2a.y);
        wv[2] = fmaxf(C1 * e1a.z, C2 * e2a.z);
        wv[3] = fmaxf(C1 * e1a.w, C2 * e2a.w);
        wv[4] = fmaxf(C1 * e1b.x, C2 * e2b.x);
        wv[5] = fmaxf(C1 * e1b.y, C2 * e2b.y);
        wv[6] = fmaxf(C1 * e1b.z, C2 * e2b.z);
        wv[7] = fmaxf(C1 * e1b.w, C2 * e2b.w);

        const unsigned int mbit = word >> (quad * 8);
        #pragma unroll
        for (int j = 0; j < 8; ++j) {
            wv[j] = ((mbit >> j) & 1u) ? wv[j] : 0.0f;
            pd += wv[j];
        }

        const uint4 packed = {pack2bf(wv[0], wv[1]), pack2bf(wv[2], wv[3]),
                              pack2bf(wv[4], wv[5]), pack2bf(wv[6], wv[7])};
        const bf16x8 bfrag = __builtin_bit_cast(bf16x8, packed);

        const int abase = cc * 256 + li * 4 + quad;
        #pragma unroll
        for (int f = 0; f < 4; ++f) {
            const bf16x8 afrag = __builtin_bit_cast(bf16x8, ap[abase + f * 64]);
            acc[f] = __builtin_amdgcn_mfma_f32_16x16x32_bf16(afrag, bfrag, acc[f], 0, 0, 0);
        }
    }

    // ---- combine the 4 k-quarters per head ----
    if (kq != 0) {
        #pragma unroll
        for (int f = 0; f < 4; ++f) {
            #pragma unroll
            for (int r = 0; r < 4; ++r) comb[hl][kq - 1][lane][f * 4 + r] = acc[f][r];
        }
        comb[hl][kq - 1][lane][16] = pd;
    }
    __syncthreads();
    if (kq == 0) {
        #pragma unroll
        for (int w = 0; w < 3; ++w) {
            #pragma unroll
            for (int f = 0; f < 4; ++f) {
                #pragma unroll
                for (int r = 0; r < 4; ++r) acc[f][r] += comb[hl][w][lane][f * 4 + r];
            }
            pd += comb[hl][w][lane][16];
        }
        pd += __shfl_xor(pd, 16, 64);
        pd += __shfl_xor(pd, 32, 64);
        const float rd = 1.0f / pd;

        float4* op = (float4*)(out + head * HT_STRIDE + (i0 + li) * 64);
        #pragma unroll
        for (int f = 0; f < 4; ++f) {
            float4 v = make_float4(acc[f][0] * rd, acc[f][1] * rd,
                                   acc[f][2] * rd, acc[f][3] * rd);
            op[f * 4 + quad] = v;   // o base = f*16 + quad*4
        }
    }
}

extern "C" void kernel_launch(void* const* d_in, const int* in_sizes, int n_in,
                              void* d_out, int out_size, void* d_ws, size_t ws_size,
                              hipStream_t stream) {
    const float* h   = (const float*)d_in[0];  // (1,4096,128) f32
    const int*   adj = (const int*)d_in[1];    // (4096,4096) i32
    const float* W   = (const float*)d_in[2];  // (128,512) f32
    const float* aW  = (const float*)d_in[3];  // (8,128,1) f32
    float* out = (float*)d_out;                // (1,8,4096,64) f32

    // ws layout:
    //   src  @ 0        (128 KB)
    //   tgt  @ 128 KB   (128 KB)
    //   tmax @ 256 KB   (4 KB slot)
    //   E1   @ 260 KB   (128 KB)
    //   E2   @ 388 KB   (128 KB)
    //   htT2 @ 516 KB   (4 MB, bf16 k-tiled)          -> 4.50 MB base
    //   bmg  @ 4.50 MB  (2 MB bitmask, optional)      -> 6.50 MB total
    char* ws = (char*)d_ws;
    float* src  = (float*)(ws);
    float* tgt  = (float*)(ws + 131072);
    float* tmax = (float*)(ws + 262144);
    float* E1   = (float*)(ws + 266240);
    float* E2   = (float*)(ws + 397312);
    unsigned short* htT2 = (unsigned short*)(ws + 528384);
    unsigned int* bmg = (unsigned int*)(ws + 4722688);
    const int use_bmg = (ws_size >= (size_t)4722688 + 2097152) ? 1 : 0;
    float* ht = out;   // ht (f32) lives in d_out; k_attn overwrites it last

    if (use_bmg)
        hipLaunchKernelGGL(k_maskbuild, dim3(1024), dim3(256), 0, stream, adj, bmg);
    hipLaunchKernelGGL(k_linear,    dim3(512),  dim3(256), 0, stream, h, W, aW, ht, src, tgt);
    hipLaunchKernelGGL(k_expmax,    dim3(8),    dim3(256), 0, stream, tgt, tmax, E1, E2);
    hipLaunchKernelGGL(k_transpose, dim3(512),  dim3(256), 0, stream, ht, htT2);
    hipLaunchKernelGGL(k_attn,      dim3(1024), dim3(512), 0, stream,
                       adj, bmg, use_bmg, htT2, src, E1, E2, tmax, out);
}

// Round 9
// 238.222 us; speedup vs baseline: 1.0197x; 1.0197x over previous
//
#include <hip/hip_runtime.h>
#include <stdint.h>

#define HT_STRIDE 262144   // 4096*64 elements per head

typedef __attribute__((ext_vector_type(8))) _Float16 f16x8;
typedef __attribute__((ext_vector_type(4))) float f32x4;

__device__ __forceinline__ unsigned int pk_mul(unsigned int a, unsigned int b) {
    unsigned int d;
    asm("v_pk_mul_f16 %0, %1, %2" : "=v"(d) : "v"(a), "v"(b));
    return d;
}
__device__ __forceinline__ unsigned int pk_max(unsigned int a, unsigned int b) {
    unsigned int d;
    asm("v_pk_max_f16 %0, %1, %2" : "=v"(d) : "v"(a), "v"(b));
    return d;
}
// full-width masks for bits b0,b0+1 of w -> low/high 16-bit lanes
__device__ __forceinline__ unsigned int bitmask2(unsigned int w, int b0) {
    int m0 = ((int)(w << (31 - b0))) >> 31;
    int m1 = ((int)(w << (30 - b0))) >> 31;
    return (((unsigned int)m0) & 0x0000FFFFu) | (((unsigned int)m1) & 0xFFFF0000u);
}
__device__ __forceinline__ unsigned int hx2(float f) {
    unsigned short s = __builtin_bit_cast(unsigned short, (_Float16)f);
    return (unsigned int)s * 0x10001u;
}

// ---------------------------------------------------------------------------
// Kernel A (fused): hW-GEMM + src/tgt projections + f16 k-tiled transpose.
// Grid 1024 = 512 rowgroups x 2 col-halves; block 256 thr, 1 col/thread.
// Reshape map (R8-proven): hW(n,c) -> head=n>>9, i=(n&511)*8+(c>>6), o=c&63.
// ---------------------------------------------------------------------------
__global__ void __launch_bounds__(256) k_linear(const float* __restrict__ h,
                                                const float* __restrict__ W,
                                                const float* __restrict__ aW,
                                                unsigned short* __restrict__ htT2h,
                                                float* __restrict__ src,
                                                float* __restrict__ tgt) {
    __shared__ float hs[8][128];
    const int t = threadIdx.x;
    const int rg = blockIdx.x >> 1, ch = blockIdx.x & 1;
    const int n0 = rg * 8, c0 = ch * 256;
    const int hb = rg >> 6;
    const int ib = (rg & 63) * 64;
    {
        float4 v = ((const float4*)(h + n0 * 128))[t];
        int e = t * 4;
        int r = e >> 7, f = e & 127;
        hs[r][f + 0] = v.x; hs[r][f + 1] = v.y;
        hs[r][f + 2] = v.z; hs[r][f + 3] = v.w;
    }
    __syncthreads();
    float acc[8];
    #pragma unroll
    for (int r = 0; r < 8; ++r) acc[r] = 0.f;
    const float* Wc = W + c0 + t;
    #pragma unroll 4
    for (int f = 0; f < 128; ++f) {
        float w = Wc[f * 512];
        #pragma unroll
        for (int r = 0; r < 8; ++r) acc[r] = fmaf(hs[r][f], w, acc[r]);
    }
    const int o = t & 63;
    const int g = (c0 >> 6) + (t >> 6);
    const float a1o = aW[hb * 128 + o];
    const float a2o = aW[hb * 128 + 64 + o];
    #pragma unroll
    for (int r = 0; r < 8; ++r) {
        float s  = acc[r] * a1o;
        float gg = acc[r] * a2o;
        #pragma unroll
        for (int off = 32; off > 0; off >>= 1) {
            s  += __shfl_down(s,  off, 64);
            gg += __shfl_down(gg, off, 64);
        }
        if ((t & 63) == 0) {
            const int i = ib + r * 8 + g;
            src[hb * 4096 + i] = s;
            tgt[hb * 4096 + i] = gg;
        }
    }
    // f16 k-tiled scatter: htT2h[hd][i>>5][o][i&31]
    #pragma unroll
    for (int r = 0; r < 8; ++r) {
        const int i = ib + r * 8 + g;
        unsigned short us = __builtin_bit_cast(unsigned short, (_Float16)acc[r]);
        htT2h[hb * HT_STRIDE + (i >> 5) * 2048 + o * 32 + (i & 31)] = us;
    }
}

// ---------------------------------------------------------------------------
// Kernel C: per head: tmax (pass 1, R8-proven) + f16 exp tables (pass 2):
// E1h = exp(tt - tmax) <= 1, E2h = exp(0.2*(tt - tmax)) <= 1  (f16-safe).
// ---------------------------------------------------------------------------
__global__ void __launch_bounds__(256) k_expmax(const float* __restrict__ tgt,
                                                float* __restrict__ tmax,
                                                unsigned short* __restrict__ E1h,
                                                unsigned short* __restrict__ E2h) {
    __shared__ float red[256];
    const int t = threadIdx.x;
    const int hd = blockIdx.x;
    float m = -1e30f;
    for (int i = t; i < 4096; i += 256) m = fmaxf(m, tgt[hd * 4096 + i]);
    red[t] = m;
    __syncthreads();
    for (int s2 = 128; s2 > 0; s2 >>= 1) {
        if (t < s2) red[t] = fmaxf(red[t], red[t + s2]);
        __syncthreads();
    }
    m = red[0];
    if (t == 0) tmax[hd] = m;
    for (int i = t; i < 4096; i += 256) {
        float v = tgt[hd * 4096 + i] - m;
        E1h[hd * 4096 + i] = __builtin_bit_cast(unsigned short, (_Float16)__expf(v));
        E2h[hd * 4096 + i] = __builtin_bit_cast(unsigned short, (_Float16)__expf(0.2f * v));
    }
}

// ---------------------------------------------------------------------------
// Kernel M: adjacency -> packed bitmask (R8-proven).
// ---------------------------------------------------------------------------
__global__ void __launch_bounds__(256) k_maskbuild(const int* __restrict__ adj,
                                                   unsigned int* __restrict__ bmg) {
    const int wave = threadIdx.x >> 6, lane = threadIdx.x & 63;
    const int row = blockIdx.x * 4 + wave;
    const int* arow = adj + row * 4096;
    #pragma unroll 4
    for (int s = 0; s < 64; ++s) {
        int v = arow[s * 64 + lane];
        unsigned long long m = __ballot(v > 0);
        if (lane < 2) bmg[row * 128 + s * 2 + lane] = (unsigned int)(m >> (lane * 32));
    }
}

// ---------------------------------------------------------------------------
// Kernel D v4: fused GAT attention, packed-f16 weights, M=32 rows/stripe.
// Grid 1024 = 128 stripes x 8 heads; block 256 thr = 4 waves = 4 k-quarters.
// Per iter (32 k): 2 mask words (uint4 per 4 iters), 2 uint4 E-loads,
// packed mul/max/mask weights for 2 row-blocks, 4 A-frags x 2 MFMAs + 2
// pd-MFMAs (ones A). LDS = 27 KB combine only; one barrier total.
// ---------------------------------------------------------------------------
__global__ void __launch_bounds__(256) k_attn(const unsigned int* __restrict__ bmg,
                                              const unsigned short* __restrict__ htT2h,
                                              const float* __restrict__ src,
                                              const unsigned short* __restrict__ E1h,
                                              const unsigned short* __restrict__ E2h,
                                              const float* __restrict__ tmax,
                                              float* __restrict__ out) {
    __shared__ float comb[3][64][35];   // writers kq1..3: 32 acc + pd1 + pd2

    const int t = threadIdx.x;
    const int kq = t >> 6, lane = t & 63;
    const int li = lane & 15, quad = lane >> 4;
    const int stripe = blockIdx.x >> 3, head = blockIdx.x & 7;
    const int i0 = stripe * 32;
    const int q8 = quad * 8;

    const float tmx = tmax[head];
    const float sv1 = src[head * 4096 + i0 + li];
    const float sv2 = src[head * 4096 + i0 + 16 + li];
    const float tm1 = sv1 + tmx, mi1 = fmaxf(tm1, 0.2f * tm1);
    const float tm2 = sv2 + tmx, mi2 = fmaxf(tm2, 0.2f * tm2);
    const unsigned int c1a = hx2(__expf(tm1 - mi1));
    const unsigned int c2a = hx2(__expf(0.2f * tm1 - mi1));
    const unsigned int c1b = hx2(__expf(tm2 - mi2));
    const unsigned int c2b = hx2(__expf(0.2f * tm2 - mi2));

    f32x4 acc1[4], acc2[4], pda, pdb;
    #pragma unroll
    for (int f = 0; f < 4; ++f) {
        acc1[f] = (f32x4){0.f, 0.f, 0.f, 0.f};
        acc2[f] = (f32x4){0.f, 0.f, 0.f, 0.f};
    }
    pda = (f32x4){0.f, 0.f, 0.f, 0.f};
    pdb = (f32x4){0.f, 0.f, 0.f, 0.f};

    const uint4 ones4 = {0x3C003C00u, 0x3C003C00u, 0x3C003C00u, 0x3C003C00u};
    const f16x8 onesf = __builtin_bit_cast(f16x8, ones4);

    const uint4* e1p = (const uint4*)(E1h + head * 4096);
    const uint4* e2p = (const uint4*)(E2h + head * 4096);
    const uint4* ap  = (const uint4*)(htT2h + head * HT_STRIDE);
    const uint4* bm1 = (const uint4*)(bmg + (i0 + li) * 128);
    const uint4* bm2 = (const uint4*)(bmg + (i0 + 16 + li) * 128);

    for (int c4 = 0; c4 < 8; ++c4) {
        const int ccb = kq * 32 + c4 * 4;
        const uint4 w4a = bm1[kq * 8 + c4];
        const uint4 w4b = bm2[kq * 8 + c4];
        const unsigned int wa[4] = {w4a.x, w4a.y, w4a.z, w4a.w};
        const unsigned int wb[4] = {w4b.x, w4b.y, w4b.z, w4b.w};
        #pragma unroll
        for (int u = 0; u < 4; ++u) {
            const int cc = ccb + u;
            const uint4 e1q = e1p[cc * 4 + quad];
            const uint4 e2q = e2p[cc * 4 + quad];
            const unsigned int word1 = wa[u], word2 = wb[u];

            uint4 b1, b2;
            b1.x = pk_max(pk_mul(c1a, e1q.x), pk_mul(c2a, e2q.x)) & bitmask2(word1, q8 + 0);
            b1.y = pk_max(pk_mul(c1a, e1q.y), pk_mul(c2a, e2q.y)) & bitmask2(word1, q8 + 2);
            b1.z = pk_max(pk_mul(c1a, e1q.z), pk_mul(c2a, e2q.z)) & bitmask2(word1, q8 + 4);
            b1.w = pk_max(pk_mul(c1a, e1q.w), pk_mul(c2a, e2q.w)) & bitmask2(word1, q8 + 6);
            b2.x = pk_max(pk_mul(c1b, e1q.x), pk_mul(c2b, e2q.x)) & bitmask2(word2, q8 + 0);
            b2.y = pk_max(pk_mul(c1b, e1q.y), pk_mul(c2b, e2q.y)) & bitmask2(word2, q8 + 2);
            b2.z = pk_max(pk_mul(c1b, e1q.z), pk_mul(c2b, e2q.z)) & bitmask2(word2, q8 + 4);
            b2.w = pk_max(pk_mul(c1b, e1q.w), pk_mul(c2b, e2q.w)) & bitmask2(word2, q8 + 6);
            const f16x8 bf1 = __builtin_bit_cast(f16x8, b1);
            const f16x8 bf2 = __builtin_bit_cast(f16x8, b2);

            const int abase = cc * 256 + li * 4 + quad;
            #pragma unroll
            for (int f = 0; f < 4; ++f) {
                const f16x8 afr = __builtin_bit_cast(f16x8, ap[abase + f * 64]);
                acc1[f] = __builtin_amdgcn_mfma_f32_16x16x32_f16(afr, bf1, acc1[f], 0, 0, 0);
                acc2[f] = __builtin_amdgcn_mfma_f32_16x16x32_f16(afr, bf2, acc2[f], 0, 0, 0);
            }
            pda = __builtin_amdgcn_mfma_f32_16x16x32_f16(onesf, bf1, pda, 0, 0, 0);
            pdb = __builtin_amdgcn_mfma_f32_16x16x32_f16(onesf, bf2, pdb, 0, 0, 0);
        }
    }

    if (kq != 0) {
        #pragma unroll
        for (int f = 0; f < 4; ++f) {
            #pragma unroll
            for (int r = 0; r < 4; ++r) {
                comb[kq - 1][lane][f * 4 + r]      = acc1[f][r];
                comb[kq - 1][lane][16 + f * 4 + r] = acc2[f][r];
            }
        }
        comb[kq - 1][lane][32] = pda[0];
        comb[kq - 1][lane][33] = pdb[0];
    }
    __syncthreads();
    if (kq == 0) {
        float pd1 = pda[0], pd2 = pdb[0];
        #pragma unroll
        for (int w = 0; w < 3; ++w) {
            #pragma unroll
            for (int f = 0; f < 4; ++f) {
                #pragma unroll
                for (int r = 0; r < 4; ++r) {
                    acc1[f][r] += comb[w][lane][f * 4 + r];
                    acc2[f][r] += comb[w][lane][16 + f * 4 + r];
                }
            }
            pd1 += comb[w][lane][32];
            pd2 += comb[w][lane][33];
        }
        const float rd1 = 1.0f / pd1;
        const float rd2 = 1.0f / pd2;
        float4* op1 = (float4*)(out + head * HT_STRIDE + (i0 + li) * 64);
        float4* op2 = (float4*)(out + head * HT_STRIDE + (i0 + 16 + li) * 64);
        #pragma unroll
        for (int f = 0; f < 4; ++f) {
            op1[f * 4 + quad] = make_float4(acc1[f][0] * rd1, acc1[f][1] * rd1,
                                            acc1[f][2] * rd1, acc1[f][3] * rd1);
            op2[f * 4 + quad] = make_float4(acc2[f][0] * rd2, acc2[f][1] * rd2,
                                            acc2[f][2] * rd2, acc2[f][3] * rd2);
        }
    }
}

extern "C" void kernel_launch(void* const* d_in, const int* in_sizes, int n_in,
                              void* d_out, int out_size, void* d_ws, size_t ws_size,
                              hipStream_t stream) {
    const float* h   = (const float*)d_in[0];  // (1,4096,128) f32
    const int*   adj = (const int*)d_in[1];    // (4096,4096) i32
    const float* W   = (const float*)d_in[2];  // (128,512) f32
    const float* aW  = (const float*)d_in[3];  // (8,128,1) f32
    float* out = (float*)d_out;                // (1,8,4096,64) f32

    // ws layout (6.38 MB; R8 proved ws >= 6.82 MB):
    //   src   @ 0        (128 KB)
    //   tgt   @ 131072   (128 KB)
    //   tmax  @ 262144   (4 KB slot)
    //   E1h   @ 266240   (64 KB, f16)
    //   E2h   @ 331776   (64 KB, f16)
    //   htT2h @ 397312   (4 MB, f16 k-tiled)
    //   bmg   @ 4591616  (2 MB bitmask)
    char* ws = (char*)d_ws;
    float* src  = (float*)(ws);
    float* tgt  = (float*)(ws + 131072);
    float* tmax = (float*)(ws + 262144);
    unsigned short* E1h = (unsigned short*)(ws + 266240);
    unsigned short* E2h = (unsigned short*)(ws + 331776);
    unsigned short* htT2h = (unsigned short*)(ws + 397312);
    unsigned int* bmg = (unsigned int*)(ws + 4591616);

    hipLaunchKernelGGL(k_maskbuild, dim3(1024), dim3(256), 0, stream, adj, bmg);
    hipLaunchKernelGGL(k_linear,    dim3(1024), dim3(256), 0, stream, h, W, aW, htT2h, src, tgt);
    hipLaunchKernelGGL(k_expmax,    dim3(8),    dim3(256), 0, stream, tgt, tmax, E1h, E2h);
    hipLaunchKernelGGL(k_attn,      dim3(1024), dim3(256), 0, stream,
                       bmg, htT2h, src, E1h, E2h, tmax, out);
}